// Round 7
// baseline (782.903 us; speedup 1.0000x reference)
//
#include <hip/hip_runtime.h>
#include <stdint.h>

#define BB 256
#define TT 2048
#define KK 64
#define CHUNK 64
#define NCHUNK (TT / CHUNK)   // 32
#define WLEN 128
#define NWIN (TT / WLEN)      // 16
#define NEG_INF_F (-10000.0f)

// DPP quad_perm helpers (free VALU cross-lane within quads)
#define DPP_XOR1 0xB1   // quad_perm [1,0,3,2]
#define DPP_XOR2 0x4E   // quad_perm [2,3,0,1]

template <int CTRL>
__device__ __forceinline__ float dpp_f(float x) {
    return __int_as_float(__builtin_amdgcn_update_dpp(
        0, __float_as_int(x), CTRL, 0xF, 0xF, true));
}
template <int CTRL>
__device__ __forceinline__ int dpp_i(int x) {
    return __builtin_amdgcn_update_dpp(0, x, CTRL, 0xF, 0xF, true);
}

// LDS-only barrier: never drains vmcnt (bp stores / window loads stay in flight)
__device__ __forceinline__ void lds_barrier() {
    asm volatile("s_waitcnt lgkmcnt(0)\n\ts_barrier" ::: "memory");
}

__device__ __forceinline__ void gload_lds16(const void* g, void* l) {
    __builtin_amdgcn_global_load_lds(
        (const __attribute__((address_space(1))) void*)g,
        (__attribute__((address_space(3))) void*)l, 16, 0, 0);
}

__global__ __launch_bounds__(512, 2)
void viterbi_fwd_bt(const float* __restrict__ feats,
                    const float* __restrict__ trans,
                    const int* __restrict__ start_tag_p,
                    const int* __restrict__ stop_tag_p,
                    float* __restrict__ out,
                    unsigned char* __restrict__ bp_ws)
{
    const int b    = blockIdx.x;
    const int tid  = threadIdx.x;
    const int lane = tid & 63;
    const int w    = __builtin_amdgcn_readfirstlane(tid >> 6);  // wave 0..7
    const bool is_fv = (w < 4);          // waves 0-3: fv producers; 4-7: bp consumers
    const int wg   = is_fv ? w : (w - 4);
    const int g    = lane >> 2;          // row within subgroup (16 rows/wave)
    const int j    = lane & 3;           // p-chunk within row (4 chunks of 16)
    const int n    = wg * 16 + g;        // owned output row
    const int pbase = j * 16;
    const bool jz  = (j == 0);

    const int start_tag = *start_tag_p;
    const int stop_tag  = *stop_tag_p;

    __shared__ float fv_lds[2][KK];          // double-buffered Viterbi variables
    __shared__ float feat_lds[2][WLEN][KK];  // 64KB feat window double buffer
    __shared__ int   cmap[NCHUNK][KK];       // composed backpointer maps
    __shared__ int   be_lds[NCHUNK];
    __shared__ int   bl_lds;

    const float* fb = feats + (size_t)b * TT * KK;
    unsigned char* bpb = bp_ws + (size_t)b * TT * KK;

    // per-lane transition fragment: trans[n][pbase .. pbase+15]
    const float4* trp = (const float4*)&trans[n * KK + pbase];
    const float4 t0 = trp[0], t1 = trp[1], t2 = trp[2], t3 = trp[3];
    const float tstop = trans[stop_tag * KK + lane];

    // feat window stage: bp waves only; each of the 4 waves fills 8KB (8 x 1KB)
    auto issue_win = [&](int widx, int bufsel) {
        const char* gsrc = (const char*)(fb + (size_t)widx * WLEN * KK)
                         + wg * 8192 + lane * 16;
        char* ldst = (char*)&feat_lds[bufsel][0][0] + wg * 8192;
#pragma unroll
        for (int k2 = 0; k2 < 8; ++k2)
            gload_lds16(gsrc + k2 * 1024, ldst + k2 * 1024);
    };

    if (tid < KK) fv_lds[0][tid] = (tid == start_tag) ? 0.0f : NEG_INF_F;
    if (!is_fv) issue_win(0, 0);
    __syncthreads();               // window 0 resident + fv init visible
    if (!is_fv) issue_win(1, 1);

    if (is_fv) {
        // ================= fv producer: max-only recurrence =================
        __builtin_amdgcn_s_setprio(1);
        for (int W = 0; W < NWIN; ++W) {
            const float (*fw)[KK] = feat_lds[W & 1];
            for (int tt = 0; tt < WLEN; ++tt) {
                const int t = W * WLEN + tt;
                const float4* fp = (const float4*)&fv_lds[t & 1][pbase];
                const float4 a0 = fp[0], a1 = fp[1], a2 = fp[2], a3 = fp[3];
                const float featval = fw[tt][n];   // 4-lane broadcast

                const float m0 = fmaxf(fmaxf(a0.x + t0.x, a0.y + t0.y),
                                       fmaxf(a0.z + t0.z, a0.w + t0.w));
                const float m1 = fmaxf(fmaxf(a1.x + t1.x, a1.y + t1.y),
                                       fmaxf(a1.z + t1.z, a1.w + t1.w));
                const float m2 = fmaxf(fmaxf(a2.x + t2.x, a2.y + t2.y),
                                       fmaxf(a2.z + t2.z, a2.w + t2.w));
                const float m3 = fmaxf(fmaxf(a3.x + t3.x, a3.y + t3.y),
                                       fmaxf(a3.z + t3.z, a3.w + t3.w));
                float m = fmaxf(fmaxf(m0, m1), fmaxf(m2, m3));
                m = fmaxf(m, dpp_f<DPP_XOR1>(m));   // quad reduce (4 lanes/row)
                m = fmaxf(m, dpp_f<DPP_XOR2>(m));

                if (jz) fv_lds[(t + 1) & 1][n] = m + featval;
                lds_barrier();
            }
            asm volatile("s_waitcnt vmcnt(0)" ::: "memory");  // trivial for fv waves
            __builtin_amdgcn_s_barrier();
        }
    } else {
        // ============== bp consumer: one step behind, reg-preloaded ==============
        float4 q0, q1, q2, q3;   // fv_{t-1} preload
        {
            const float4* fp = (const float4*)&fv_lds[0][pbase];
            q0 = fp[0]; q1 = fp[1]; q2 = fp[2]; q3 = fp[3];
        }
        for (int W = 0; W < NWIN; ++W) {
            for (int tt = 0; tt < WLEN; ++tt) {
                const int t = W * WLEN + tt;
                if (t > 0) {
                    // candidates for step t-1 from registers (no LDS latency)
                    const float v0  = q0.x + t0.x, v1  = q0.y + t0.y;
                    const float v2  = q0.z + t0.z, v3  = q0.w + t0.w;
                    const float v4  = q1.x + t1.x, v5  = q1.y + t1.y;
                    const float v6  = q1.z + t1.z, v7  = q1.w + t1.w;
                    const float v8  = q2.x + t2.x, v9  = q2.y + t2.y;
                    const float v10 = q2.z + t2.z, v11 = q2.w + t2.w;
                    const float v12 = q3.x + t3.x, v13 = q3.y + t3.y;
                    const float v14 = q3.z + t3.z, v15 = q3.w + t3.w;
                    // max (order-independent == fv wave's value exactly)
                    const float ma = fmaxf(fmaxf(v0, v1), fmaxf(v2, v3));
                    const float mb = fmaxf(fmaxf(v4, v5), fmaxf(v6, v7));
                    const float mc = fmaxf(fmaxf(v8, v9), fmaxf(v10, v11));
                    const float md = fmaxf(fmaxf(v12, v13), fmaxf(v14, v15));
                    float m = fmaxf(fmaxf(ma, mb), fmaxf(mc, md));
                    m = fmaxf(m, dpp_f<DPP_XOR1>(m));
                    m = fmaxf(m, dpp_f<DPP_XOR2>(m));
                    // first-match eq-scan (inline-const indices)
                    const int s0  = (v0  == m) ?  0 : 127;
                    const int s1  = (v1  == m) ?  1 : 127;
                    const int s2  = (v2  == m) ?  2 : 127;
                    const int s3  = (v3  == m) ?  3 : 127;
                    const int s4  = (v4  == m) ?  4 : 127;
                    const int s5  = (v5  == m) ?  5 : 127;
                    const int s6  = (v6  == m) ?  6 : 127;
                    const int s7  = (v7  == m) ?  7 : 127;
                    const int s8  = (v8  == m) ?  8 : 127;
                    const int s9  = (v9  == m) ?  9 : 127;
                    const int s10 = (v10 == m) ? 10 : 127;
                    const int s11 = (v11 == m) ? 11 : 127;
                    const int s12 = (v12 == m) ? 12 : 127;
                    const int s13 = (v13 == m) ? 13 : 127;
                    const int s14 = (v14 == m) ? 14 : 127;
                    const int s15 = (v15 == m) ? 15 : 127;
                    int sl = min(min(min(min(s0, s1), min(s2, s3)),
                                     min(min(s4, s5), min(s6, s7))),
                                 min(min(min(s8, s9), min(s10, s11)),
                                     min(min(s12, s13), min(s14, s15))));
                    int idx = sl + pbase;                 // 127+pbase never wins
                    idx = min(idx, dpp_i<DPP_XOR1>(idx));
                    idx = min(idx, dpp_i<DPP_XOR2>(idx)); // smallest matching p
                    if (jz) bpb[(size_t)(t - 1) * KK + n] = (unsigned char)idx;
                }
                // preload fv_t (written by fv waves at step t-1, stable now)
                const float4* fp = (const float4*)&fv_lds[t & 1][pbase];
                q0 = fp[0]; q1 = fp[1]; q2 = fp[2]; q3 = fp[3];
                lds_barrier();
            }
            asm volatile("s_waitcnt vmcnt(0)" ::: "memory");  // drain window loads + bp stores
            __builtin_amdgcn_s_barrier();
            if (W + 2 < NWIN) issue_win(W + 2, W & 1);
        }
        // trailing bp for t = TT-1 from q = fv_{TT-1}
        {
            const float v0  = q0.x + t0.x, v1  = q0.y + t0.y;
            const float v2  = q0.z + t0.z, v3  = q0.w + t0.w;
            const float v4  = q1.x + t1.x, v5  = q1.y + t1.y;
            const float v6  = q1.z + t1.z, v7  = q1.w + t1.w;
            const float v8  = q2.x + t2.x, v9  = q2.y + t2.y;
            const float v10 = q2.z + t2.z, v11 = q2.w + t2.w;
            const float v12 = q3.x + t3.x, v13 = q3.y + t3.y;
            const float v14 = q3.z + t3.z, v15 = q3.w + t3.w;
            const float ma = fmaxf(fmaxf(v0, v1), fmaxf(v2, v3));
            const float mb = fmaxf(fmaxf(v4, v5), fmaxf(v6, v7));
            const float mc = fmaxf(fmaxf(v8, v9), fmaxf(v10, v11));
            const float md = fmaxf(fmaxf(v12, v13), fmaxf(v14, v15));
            float m = fmaxf(fmaxf(ma, mb), fmaxf(mc, md));
            m = fmaxf(m, dpp_f<DPP_XOR1>(m));
            m = fmaxf(m, dpp_f<DPP_XOR2>(m));
            const int s0  = (v0  == m) ?  0 : 127;
            const int s1  = (v1  == m) ?  1 : 127;
            const int s2  = (v2  == m) ?  2 : 127;
            const int s3  = (v3  == m) ?  3 : 127;
            const int s4  = (v4  == m) ?  4 : 127;
            const int s5  = (v5  == m) ?  5 : 127;
            const int s6  = (v6  == m) ?  6 : 127;
            const int s7  = (v7  == m) ?  7 : 127;
            const int s8  = (v8  == m) ?  8 : 127;
            const int s9  = (v9  == m) ?  9 : 127;
            const int s10 = (v10 == m) ? 10 : 127;
            const int s11 = (v11 == m) ? 11 : 127;
            const int s12 = (v12 == m) ? 12 : 127;
            const int s13 = (v13 == m) ? 13 : 127;
            const int s14 = (v14 == m) ? 14 : 127;
            const int s15 = (v15 == m) ? 15 : 127;
            int sl = min(min(min(min(s0, s1), min(s2, s3)),
                             min(min(s4, s5), min(s6, s7))),
                         min(min(min(s8, s9), min(s10, s11)),
                             min(min(s12, s13), min(s14, s15))));
            int idx = sl + pbase;
            idx = min(idx, dpp_i<DPP_XOR1>(idx));
            idx = min(idx, dpp_i<DPP_XOR2>(idx));
            if (jz) bpb[(size_t)(TT - 1) * KK + n] = (unsigned char)idx;
        }
    }

    __syncthreads();   // full drain: all bp stores visible block-wide

    // ---- chunk-map composition: wave w composes chunks 4w..4w+3 ----
    {
        const int c0 = w * 4;
        const unsigned char* q0 = bpb + (size_t)(c0 + 0) * CHUNK * KK + lane;
        const unsigned char* q1 = bpb + (size_t)(c0 + 1) * CHUNK * KK + lane;
        const unsigned char* q2 = bpb + (size_t)(c0 + 2) * CHUNK * KK + lane;
        const unsigned char* q3 = bpb + (size_t)(c0 + 3) * CHUNK * KK + lane;
        int M0 = lane, M1 = lane, M2 = lane, M3 = lane;
        int a0 = q0[0], a1 = q1[0], a2 = q2[0], a3 = q3[0];
        int b0 = q0[KK], b1 = q1[KK], b2 = q2[KK], b3 = q3[KK];
        for (int t = 0; t < CHUNK; t += 2) {
            int n0 = 0, n1 = 0, n2 = 0, n3 = 0, m0 = 0, m1 = 0, m2 = 0, m3 = 0;
            if (t + 2 < CHUNK) {
                n0 = q0[(t + 2) * KK]; n1 = q1[(t + 2) * KK];
                n2 = q2[(t + 2) * KK]; n3 = q3[(t + 2) * KK];
                m0 = q0[(t + 3) * KK]; m1 = q1[(t + 3) * KK];
                m2 = q2[(t + 3) * KK]; m3 = q3[(t + 3) * KK];
            }
            M0 = __shfl(M0, a0); M1 = __shfl(M1, a1);
            M2 = __shfl(M2, a2); M3 = __shfl(M3, a3);
            M0 = __shfl(M0, b0); M1 = __shfl(M1, b1);
            M2 = __shfl(M2, b2); M3 = __shfl(M3, b3);
            a0 = n0; a1 = n1; a2 = n2; a3 = n3;
            b0 = m0; b1 = m1; b2 = m2; b3 = m3;
        }
        cmap[c0 + 0][lane] = M0; cmap[c0 + 1][lane] = M1;
        cmap[c0 + 2][lane] = M2; cmap[c0 + 3][lane] = M3;
    }

    // ---- terminal argmax (wave 0, butterfly, first-max tie-break) ----
    if (w == 0) {
        float bv = fv_lds[TT & 1][lane] + tstop;   // TT even -> buffer 0
        int bi = lane;
#pragma unroll
        for (int off = 1; off < 64; off <<= 1) {
            const float ov = __shfl_xor(bv, off);
            const int   oi = __shfl_xor(bi, off);
            const bool take = (ov > bv) || (ov == bv && oi < bi);
            bv = take ? ov : bv;
            bi = take ? oi : bi;
        }
        if (lane == 0) { out[b] = bv; bl_lds = bi; }
    }
    __syncthreads();

    // ---- chunk-boundary tags via composed maps (serial, 32 LDS hops) ----
    if (tid == 0) {
        int x = bl_lds;
        be_lds[NCHUNK - 1] = x;
        for (int c = NCHUNK - 1; c >= 1; --c) {
            x = cmap[c][x];
            be_lds[c - 1] = x;
        }
    }
    __syncthreads();

    // ---- parallel interior backtrace (32 chunks, one lane each) ----
    if (tid < NCHUNK) {
        const int c = tid;
        int x = be_lds[c];
        float* po = out + BB + (size_t)b * TT;
        for (int t = (c + 1) * CHUNK - 1; t >= c * CHUNK; --t) {
            po[t] = (float)x;
            x = (int)bpb[(size_t)t * KK + x];
        }
    }
}

extern "C" void kernel_launch(void* const* d_in, const int* in_sizes, int n_in,
                              void* d_out, int out_size, void* d_ws, size_t ws_size,
                              hipStream_t stream) {
    const float* feats = (const float*)d_in[0];
    const float* trans = (const float*)d_in[1];
    const int* start_tag = (const int*)d_in[2];
    const int* stop_tag  = (const int*)d_in[3];
    float* out = (float*)d_out;
    unsigned char* bp = (unsigned char*)d_ws;   // B*T*K = 33.5 MB backpointers

    viterbi_fwd_bt<<<BB, 512, 0, stream>>>(feats, trans, start_tag, stop_tag, out, bp);
}

// Round 8
// 432.495 us; speedup vs baseline: 1.8102x; 1.8102x over previous
//
#include <hip/hip_runtime.h>
#include <stdint.h>

#define BB 256
#define TT 2048
#define KK 64
#define CHUNK 64
#define NCHUNK (TT / CHUNK)   // 32
#define WLEN 128
#define WARM 128
#define SEG 1024              // owned steps of segment 0; segment 1 owns [SEG,TT)
#define NEG_INF_F (-10000.0f)

// DPP cross-lane helpers (free VALU permutes within 16-lane rows)
#define DPP_XOR1 0xB1   // quad_perm [1,0,3,2]
#define DPP_XOR2 0x4E   // quad_perm [2,3,0,1]
#define DPP_HMIR 0x141  // row_half_mirror (== xor4 once quads reduced)

template <int CTRL>
__device__ __forceinline__ float dpp_f(float x) {
    return __int_as_float(__builtin_amdgcn_update_dpp(
        0, __float_as_int(x), CTRL, 0xF, 0xF, true));
}
template <int CTRL>
__device__ __forceinline__ int dpp_i(int x) {
    return __builtin_amdgcn_update_dpp(0, x, CTRL, 0xF, 0xF, true);
}

// LDS-only barrier: never drains vmcnt (bp stores / window loads stay in flight)
__device__ __forceinline__ void lds_barrier() {
    asm volatile("s_waitcnt lgkmcnt(0)\n\ts_barrier" ::: "memory");
}

__device__ __forceinline__ void gload_lds16(const void* g, void* l) {
    __builtin_amdgcn_global_load_lds(
        (const __attribute__((address_space(1))) void*)g,
        (__attribute__((address_space(3))) void*)l, 16, 0, 0);
}

// ============================ kernel 1: forward ============================
// grid 512: block = (batch b = idx>>1, segment s = idx&1).
// s=0: true init, steps [0,1024). s=1: fv=0 init at t=896, 128-step warmup
// (no bp), owns [1024,2048). bp bytes -> ws. s=1 writes terminal argmax to out[b].
__global__ __launch_bounds__(512, 2)
void viterbi_fwd_seg(const float* __restrict__ feats,
                     const float* __restrict__ trans,
                     const int* __restrict__ start_tag_p,
                     const int* __restrict__ stop_tag_p,
                     float* __restrict__ out,
                     unsigned char* __restrict__ bp_ws)
{
    const int bid  = blockIdx.x;
    const int b    = bid >> 1;
    const int s    = bid & 1;
    const int t0   = s ? (SEG - WARM) : 0;          // 896 : 0
    const int L    = s ? (TT - SEG + WARM) : SEG;   // 1152 : 1024
    const int NW   = L / WLEN;                      // 9 : 8
    const int gate = s ? WARM : 0;

    const int tid  = threadIdx.x;
    const int lane = tid & 63;
    const int w    = __builtin_amdgcn_readfirstlane(tid >> 6);  // wave 0..7
    const int g    = lane >> 3;        // row group within wave
    const int j    = lane & 7;         // p-chunk within row
    const int n    = w * 8 + g;        // owned output row
    const int pbase = j * 8;
    const bool jz  = (j == 0);

    const int start_tag = *start_tag_p;
    const int stop_tag  = *stop_tag_p;

    __shared__ float fv_lds[2][KK];          // double-buffered Viterbi variables
    __shared__ float feat_lds[2][WLEN][KK];  // 64KB feat window double buffer

    const float* fb0 = feats + (size_t)b * TT * KK + (size_t)t0 * KK;
    unsigned char* bpb = bp_ws + (size_t)b * TT * KK;

    // async window stage: wave w fills its 4KB slice, 4 x 1KB issues (linear)
    auto issue_win = [&](int widx, int bufsel) {
        const char* gsrc = (const char*)(fb0 + (size_t)widx * WLEN * KK)
                         + w * 4096 + lane * 16;
        char* ldst = (char*)&feat_lds[bufsel][0][0] + w * 4096;
#pragma unroll
        for (int k2 = 0; k2 < 4; ++k2)
            gload_lds16(gsrc + k2 * 1024, ldst + k2 * 1024);
    };
    issue_win(0, 0);

    // per-lane transition fragment: trans[n][pbase .. pbase+7]
    const float4* trp = (const float4*)&trans[n * KK + pbase];
    const float4 tA = trp[0], tB = trp[1];
    const float tstop = trans[stop_tag * KK + lane];

    if (tid < KK)
        fv_lds[0][tid] = s ? 0.0f : ((tid == start_tag) ? 0.0f : NEG_INF_F);

    __syncthreads();   // drains vmcnt(0): window 0 resident + fv init visible
    issue_win(1, 1);

    // previous-step state for the deferred argmax
    float4 pA = make_float4(0, 0, 0, 0), pB = make_float4(0, 0, 0, 0);
    float  pmax = 0.0f;

    auto step = [&](int tau, const float* frow) {
        // issue LDS reads for step tau (latency overlapped by deferred argmax)
        const float4* fp = (const float4*)&fv_lds[tau & 1][pbase];
        const float4 fa = fp[0], fc = fp[1];
        const float featval = frow[n];     // 8-lane broadcast, conflict-free

        // deferred argmax + bp store for step tau-1 (register-only inputs)
        if (tau > gate) {
            const int s0 = (pA.x == pmax) ? 0 : 64;   // sentinel 64 = inline const
            const int s1 = (pA.y == pmax) ? 1 : 64;
            const int s2 = (pA.z == pmax) ? 2 : 64;
            const int s3 = (pA.w == pmax) ? 3 : 64;
            const int s4 = (pB.x == pmax) ? 4 : 64;
            const int s5 = (pB.y == pmax) ? 5 : 64;
            const int s6 = (pB.z == pmax) ? 6 : 64;
            const int s7 = (pB.w == pmax) ? 7 : 64;
            const int m1 = min(min(s0, s1), s2);   // v_min3
            const int m2 = min(min(s3, s4), s5);
            const int m3 = min(s6, s7);
            int idx = min(min(m1, m2), m3) + pbase;
            idx = min(idx, dpp_i<DPP_XOR1>(idx));
            idx = min(idx, dpp_i<DPP_XOR2>(idx));
            idx = min(idx, dpp_i<DPP_HMIR>(idx));  // smallest matching p
            if (jz) bpb[(size_t)(t0 + tau - 1) * KK + n] = (unsigned char)idx;
        }

        // scores for this lane's 8 p's
        float4 vA, vB;
        vA.x = fa.x + tA.x; vA.y = fa.y + tA.y;
        vA.z = fa.z + tA.z; vA.w = fa.w + tA.w;
        vB.x = fc.x + tB.x; vB.y = fc.y + tB.y;
        vB.z = fc.z + tB.z; vB.w = fc.w + tB.w;

        // in-lane max (v_max3-friendly)
        const float ma = fmaxf(fmaxf(vA.x, vA.y), vA.z);
        const float mb = fmaxf(fmaxf(vA.w, vB.x), vB.y);
        const float mc = fmaxf(vB.z, vB.w);
        float m = fmaxf(fmaxf(ma, mb), mc);
        // cross-lane max over the 8 lanes of this row (free DPP)
        m = fmaxf(m, dpp_f<DPP_XOR1>(m));
        m = fmaxf(m, dpp_f<DPP_XOR2>(m));
        m = fmaxf(m, dpp_f<DPP_HMIR>(m));

        if (jz) fv_lds[(tau + 1) & 1][n] = m + featval;

        pA = vA; pB = vB; pmax = m;
        lds_barrier();
    };

    for (int W = 0; W < NW; ++W) {
        const float (*fw)[KK] = feat_lds[W & 1];
        const int base = W * WLEN;
        for (int tt = 0; tt < WLEN; tt += 4) {
            step(base + tt + 0, fw[tt + 0]);
            step(base + tt + 1, fw[tt + 1]);
            step(base + tt + 2, fw[tt + 2]);
            step(base + tt + 3, fw[tt + 3]);
        }
        // boundary: window W+1 (issued one window ago) must be resident
        asm volatile("s_waitcnt vmcnt(0)" ::: "memory");
        __builtin_amdgcn_s_barrier();
        if (W + 2 < NW) issue_win(W + 2, W & 1);   // overwrite just-read buffer
    }

    // trailing argmax for tau = L-1 (t = t0+L-1, always owned)
    {
        const int s0 = (pA.x == pmax) ? 0 : 64;
        const int s1 = (pA.y == pmax) ? 1 : 64;
        const int s2 = (pA.z == pmax) ? 2 : 64;
        const int s3 = (pA.w == pmax) ? 3 : 64;
        const int s4 = (pB.x == pmax) ? 4 : 64;
        const int s5 = (pB.y == pmax) ? 5 : 64;
        const int s6 = (pB.z == pmax) ? 6 : 64;
        const int s7 = (pB.w == pmax) ? 7 : 64;
        const int m1 = min(min(s0, s1), s2);
        const int m2 = min(min(s3, s4), s5);
        const int m3 = min(s6, s7);
        int idx = min(min(m1, m2), m3) + pbase;
        idx = min(idx, dpp_i<DPP_XOR1>(idx));
        idx = min(idx, dpp_i<DPP_XOR2>(idx));
        idx = min(idx, dpp_i<DPP_HMIR>(idx));
        if (jz) bpb[(size_t)(t0 + L - 1) * KK + n] = (unsigned char)idx;
    }

    // terminal argmax (segment 1 only): coalesced fv => exact argmax; value has
    // an unknown warmup offset so the score is recomputed from the path in k2.
    if (s == 1 && w == 0) {
        float bv = fv_lds[L & 1][lane] + tstop;   // L=1152 even -> buffer 0
        int bi = lane;
#pragma unroll
        for (int off = 1; off < 64; off <<= 1) {
            const float ov = __shfl_xor(bv, off);
            const int   oi = __shfl_xor(bi, off);
            const bool take = (ov > bv) || (ov == bv && oi < bi);
            bv = take ? ov : bv;
            bi = take ? oi : bi;
        }
        if (lane == 0) out[b] = (float)bi;   // carrier for bestlast -> k2
    }
}

// ====================== kernel 2: backtrace + score ======================
__global__ __launch_bounds__(512)
void viterbi_bt_score(const float* __restrict__ feats,
                      const float* __restrict__ trans,
                      const int* __restrict__ start_tag_p,
                      const int* __restrict__ stop_tag_p,
                      float* __restrict__ out,
                      const unsigned char* __restrict__ bp_ws)
{
    const int b    = blockIdx.x;
    const int tid  = threadIdx.x;
    const int lane = tid & 63;
    const int w    = __builtin_amdgcn_readfirstlane(tid >> 6);  // 0..7

    __shared__ int cmap[NCHUNK][KK];
    __shared__ int be_lds[NCHUNK];
    __shared__ unsigned char path_lds[TT];
    __shared__ float red_lds[8];

    const unsigned char* bpb = bp_ws + (size_t)b * TT * KK;

    // ---- chunk-map composition: wave w composes chunks 4w..4w+3 ----
    {
        const int c0 = w * 4;
        const unsigned char* q0 = bpb + (size_t)(c0 + 0) * CHUNK * KK + lane;
        const unsigned char* q1 = bpb + (size_t)(c0 + 1) * CHUNK * KK + lane;
        const unsigned char* q2 = bpb + (size_t)(c0 + 2) * CHUNK * KK + lane;
        const unsigned char* q3 = bpb + (size_t)(c0 + 3) * CHUNK * KK + lane;
        int M0 = lane, M1 = lane, M2 = lane, M3 = lane;
        int a0 = q0[0], a1 = q1[0], a2 = q2[0], a3 = q3[0];
        int b0 = q0[KK], b1 = q1[KK], b2 = q2[KK], b3 = q3[KK];
        for (int t = 0; t < CHUNK; t += 2) {
            int n0 = 0, n1 = 0, n2 = 0, n3 = 0, m0 = 0, m1 = 0, m2 = 0, m3 = 0;
            if (t + 2 < CHUNK) {
                n0 = q0[(t + 2) * KK]; n1 = q1[(t + 2) * KK];
                n2 = q2[(t + 2) * KK]; n3 = q3[(t + 2) * KK];
                m0 = q0[(t + 3) * KK]; m1 = q1[(t + 3) * KK];
                m2 = q2[(t + 3) * KK]; m3 = q3[(t + 3) * KK];
            }
            M0 = __shfl(M0, a0); M1 = __shfl(M1, a1);
            M2 = __shfl(M2, a2); M3 = __shfl(M3, a3);
            M0 = __shfl(M0, b0); M1 = __shfl(M1, b1);
            M2 = __shfl(M2, b2); M3 = __shfl(M3, b3);
            a0 = n0; a1 = n1; a2 = n2; a3 = n3;
            b0 = m0; b1 = m1; b2 = m2; b3 = m3;
        }
        cmap[c0 + 0][lane] = M0; cmap[c0 + 1][lane] = M1;
        cmap[c0 + 2][lane] = M2; cmap[c0 + 3][lane] = M3;
    }
    __syncthreads();

    // ---- chunk-boundary tags (serial, 32 LDS hops) ----
    if (tid == 0) {
        int x = (int)out[b];          // bestlast from k1
        be_lds[NCHUNK - 1] = x;
        for (int c = NCHUNK - 1; c >= 1; --c) {
            x = cmap[c][x];
            be_lds[c - 1] = x;
        }
    }
    __syncthreads();

    // ---- parallel interior backtrace (32 chunks), also fill path_lds ----
    if (tid < NCHUNK) {
        const int c = tid;
        int x = be_lds[c];
        float* po = out + BB + (size_t)b * TT;
        for (int t = (c + 1) * CHUNK - 1; t >= c * CHUNK; --t) {
            po[t] = (float)x;
            path_lds[t] = (unsigned char)x;
            x = (int)bpb[(size_t)t * KK + x];
        }
    }
    __syncthreads();

    // ---- exact score recompute along the decoded path ----
    const float* fbb = feats + (size_t)b * TT * KK;
    const int start_tag = *start_tag_p;
    const int stop_tag  = *stop_tag_p;
    float acc = 0.0f;
    for (int t = tid; t < TT; t += 512) {
        const int xt = path_lds[t];
        const int xp = (t > 0) ? (int)path_lds[t - 1] : start_tag;
        acc += fbb[(size_t)t * KK + xt] + trans[xt * KK + xp];
    }
    if (tid == 0) acc += trans[stop_tag * KK + (int)path_lds[TT - 1]];
#pragma unroll
    for (int off = 1; off < 64; off <<= 1) acc += __shfl_xor(acc, off);
    if (lane == 0) red_lds[w] = acc;
    __syncthreads();
    if (tid == 0) {
        float sc = 0.0f;
        for (int i = 0; i < 8; ++i) sc += red_lds[i];
        out[b] = sc;
    }
}

extern "C" void kernel_launch(void* const* d_in, const int* in_sizes, int n_in,
                              void* d_out, int out_size, void* d_ws, size_t ws_size,
                              hipStream_t stream) {
    const float* feats = (const float*)d_in[0];
    const float* trans = (const float*)d_in[1];
    const int* start_tag = (const int*)d_in[2];
    const int* stop_tag  = (const int*)d_in[3];
    float* out = (float*)d_out;
    unsigned char* bp = (unsigned char*)d_ws;   // B*T*K = 33.5 MB backpointers

    viterbi_fwd_seg<<<BB * 2, 512, 0, stream>>>(feats, trans, start_tag, stop_tag, out, bp);
    viterbi_bt_score<<<BB, 512, 0, stream>>>(feats, trans, start_tag, stop_tag, out, bp);
}

// Round 9
// 361.709 us; speedup vs baseline: 2.1645x; 1.1957x over previous
//
#include <hip/hip_runtime.h>
#include <stdint.h>

#define BB 256
#define TT 2048
#define KK 64
#define CHUNK 64
#define NCHUNK (TT / CHUNK)   // 32
#define WLEN 64
#define WARM 128
#define NSEG 4
#define SEGLEN (TT / NSEG)    // 512
#define NEG_INF_F (-10000.0f)

// DPP cross-lane helpers (free VALU permutes within 16-lane rows)
#define DPP_XOR1 0xB1   // quad_perm [1,0,3,2]
#define DPP_XOR2 0x4E   // quad_perm [2,3,0,1]
#define DPP_HMIR 0x141  // row_half_mirror (== xor4 once quads reduced)

template <int CTRL>
__device__ __forceinline__ float dpp_f(float x) {
    return __int_as_float(__builtin_amdgcn_update_dpp(
        0, __float_as_int(x), CTRL, 0xF, 0xF, true));
}
template <int CTRL>
__device__ __forceinline__ int dpp_i(int x) {
    return __builtin_amdgcn_update_dpp(0, x, CTRL, 0xF, 0xF, true);
}

// LDS-only barrier: never drains vmcnt (bp stores / window loads stay in flight)
__device__ __forceinline__ void lds_barrier() {
    asm volatile("s_waitcnt lgkmcnt(0)\n\ts_barrier" ::: "memory");
}

__device__ __forceinline__ void gload_lds16(const void* g, void* l) {
    __builtin_amdgcn_global_load_lds(
        (const __attribute__((address_space(1))) void*)g,
        (__attribute__((address_space(3))) void*)l, 16, 0, 0);
}

// ============================ kernel 1: forward ============================
// grid 1024: block = (batch b = idx>>2, segment s = idx&3).
// s=0: true init, owns [0,512). s>0: fv=0 init at 512s-128, 128-step warmup
// (no bp), owns [512s, 512s+512). bp bytes -> ws. s=3 writes bestlast to out[b].
__global__ __launch_bounds__(512, 8)
void viterbi_fwd_seg(const float* __restrict__ feats,
                     const float* __restrict__ trans,
                     const int* __restrict__ start_tag_p,
                     const int* __restrict__ stop_tag_p,
                     float* __restrict__ out,
                     unsigned char* __restrict__ bp_ws)
{
    const int bid  = blockIdx.x;
    const int b    = bid >> 2;
    const int s    = bid & 3;
    const int t0   = s * SEGLEN - (s ? WARM : 0);
    const int L    = SEGLEN + (s ? WARM : 0);       // 512 or 640
    const int NW   = L / WLEN;                      // 8 or 10
    const int gate = s ? WARM : 0;

    const int tid  = threadIdx.x;
    const int lane = tid & 63;
    const int w    = __builtin_amdgcn_readfirstlane(tid >> 6);  // wave 0..7
    const int g    = lane >> 3;        // row group within wave
    const int j    = lane & 7;         // p-chunk within row
    const int n    = w * 8 + g;        // owned output row
    const int pbase = j * 8;
    const bool jz  = (j == 0);

    const int start_tag = *start_tag_p;
    const int stop_tag  = *stop_tag_p;

    __shared__ float fv_lds[2][KK];          // double-buffered Viterbi variables
    __shared__ float feat_lds[2][WLEN][KK];  // 32KB feat window double buffer

    const float* fb0 = feats + (size_t)b * TT * KK + (size_t)t0 * KK;
    unsigned char* bpb = bp_ws + (size_t)b * TT * KK;

    // async window stage: wave w fills its 2KB slice, 2 x 1KB issues (linear)
    auto issue_win = [&](int widx, int bufsel) {
        const char* gsrc = (const char*)(fb0 + (size_t)widx * WLEN * KK)
                         + w * 2048 + lane * 16;
        char* ldst = (char*)&feat_lds[bufsel][0][0] + w * 2048;
        gload_lds16(gsrc, ldst);
        gload_lds16(gsrc + 1024, ldst + 1024);
    };
    issue_win(0, 0);

    // per-lane transition fragment: trans[n][pbase .. pbase+7]
    const float4* trp = (const float4*)&trans[n * KK + pbase];
    const float4 tA = trp[0], tB = trp[1];
    const float tstop = trans[stop_tag * KK + lane];

    if (tid < KK)
        fv_lds[0][tid] = s ? 0.0f : ((tid == start_tag) ? 0.0f : NEG_INF_F);

    __syncthreads();   // drains vmcnt(0): window 0 resident + fv init visible
    issue_win(1, 1);

    // previous-step state for the deferred argmax
    float4 pA = make_float4(0, 0, 0, 0), pB = make_float4(0, 0, 0, 0);
    float  pmax = 0.0f;

    auto step = [&](int tau, const float* frow) {
        // issue LDS reads for step tau (latency overlapped by deferred argmax)
        const float4* fp = (const float4*)&fv_lds[tau & 1][pbase];
        const float4 fa = fp[0], fc = fp[1];
        const float featval = frow[n];     // 8-lane broadcast, conflict-free

        // deferred argmax + bp store for step tau-1 (register-only inputs)
        if (tau > gate) {
            const int s0 = (pA.x == pmax) ? 0 : 64;   // sentinel 64 = inline const
            const int s1 = (pA.y == pmax) ? 1 : 64;
            const int s2 = (pA.z == pmax) ? 2 : 64;
            const int s3 = (pA.w == pmax) ? 3 : 64;
            const int s4 = (pB.x == pmax) ? 4 : 64;
            const int s5 = (pB.y == pmax) ? 5 : 64;
            const int s6 = (pB.z == pmax) ? 6 : 64;
            const int s7 = (pB.w == pmax) ? 7 : 64;
            const int m1 = min(min(s0, s1), s2);   // v_min3
            const int m2 = min(min(s3, s4), s5);
            const int m3 = min(s6, s7);
            int idx = min(min(m1, m2), m3) + pbase;
            idx = min(idx, dpp_i<DPP_XOR1>(idx));
            idx = min(idx, dpp_i<DPP_XOR2>(idx));
            idx = min(idx, dpp_i<DPP_HMIR>(idx));  // smallest matching p
            if (jz) bpb[(size_t)(t0 + tau - 1) * KK + n] = (unsigned char)idx;
        }

        // scores for this lane's 8 p's
        float4 vA, vB;
        vA.x = fa.x + tA.x; vA.y = fa.y + tA.y;
        vA.z = fa.z + tA.z; vA.w = fa.w + tA.w;
        vB.x = fc.x + tB.x; vB.y = fc.y + tB.y;
        vB.z = fc.z + tB.z; vB.w = fc.w + tB.w;

        // in-lane max (v_max3-friendly)
        const float ma = fmaxf(fmaxf(vA.x, vA.y), vA.z);
        const float mb = fmaxf(fmaxf(vA.w, vB.x), vB.y);
        const float mc = fmaxf(vB.z, vB.w);
        float m = fmaxf(fmaxf(ma, mb), mc);
        // cross-lane max over the 8 lanes of this row (free DPP)
        m = fmaxf(m, dpp_f<DPP_XOR1>(m));
        m = fmaxf(m, dpp_f<DPP_XOR2>(m));
        m = fmaxf(m, dpp_f<DPP_HMIR>(m));

        if (jz) fv_lds[(tau + 1) & 1][n] = m + featval;

        pA = vA; pB = vB; pmax = m;
        lds_barrier();
    };

    for (int W = 0; W < NW; ++W) {
        const float (*fw)[KK] = feat_lds[W & 1];
        const int base = W * WLEN;
        for (int tt = 0; tt < WLEN; tt += 4) {
            step(base + tt + 0, fw[tt + 0]);
            step(base + tt + 1, fw[tt + 1]);
            step(base + tt + 2, fw[tt + 2]);
            step(base + tt + 3, fw[tt + 3]);
        }
        // boundary: window W+1 (issued one window ago) must be resident
        asm volatile("s_waitcnt vmcnt(0)" ::: "memory");
        __builtin_amdgcn_s_barrier();
        if (W + 2 < NW) issue_win(W + 2, W & 1);   // overwrite just-read buffer
    }

    // trailing argmax for tau = L-1 (t = t0+L-1, always owned)
    {
        const int s0 = (pA.x == pmax) ? 0 : 64;
        const int s1 = (pA.y == pmax) ? 1 : 64;
        const int s2 = (pA.z == pmax) ? 2 : 64;
        const int s3 = (pA.w == pmax) ? 3 : 64;
        const int s4 = (pB.x == pmax) ? 4 : 64;
        const int s5 = (pB.y == pmax) ? 5 : 64;
        const int s6 = (pB.z == pmax) ? 6 : 64;
        const int s7 = (pB.w == pmax) ? 7 : 64;
        const int m1 = min(min(s0, s1), s2);
        const int m2 = min(min(s3, s4), s5);
        const int m3 = min(s6, s7);
        int idx = min(min(m1, m2), m3) + pbase;
        idx = min(idx, dpp_i<DPP_XOR1>(idx));
        idx = min(idx, dpp_i<DPP_XOR2>(idx));
        idx = min(idx, dpp_i<DPP_HMIR>(idx));
        if (jz) bpb[(size_t)(t0 + L - 1) * KK + n] = (unsigned char)idx;
    }

    // terminal argmax (last segment only): warmup offset cancels in argmax;
    // the true score is recomputed from the decoded path in kernel 2.
    if (s == NSEG - 1 && w == 0) {
        float bv = fv_lds[L & 1][lane] + tstop;   // L=640 even -> buffer 0
        int bi = lane;
#pragma unroll
        for (int off = 1; off < 64; off <<= 1) {
            const float ov = __shfl_xor(bv, off);
            const int   oi = __shfl_xor(bi, off);
            const bool take = (ov > bv) || (ov == bv && oi < bi);
            bv = take ? ov : bv;
            bi = take ? oi : bi;
        }
        if (lane == 0) out[b] = (float)bi;   // carrier for bestlast -> k2
    }
}

// ====================== kernel 2: backtrace + score ======================
__global__ __launch_bounds__(512)
void viterbi_bt_score(const float* __restrict__ feats,
                      const float* __restrict__ trans,
                      const int* __restrict__ start_tag_p,
                      const int* __restrict__ stop_tag_p,
                      float* __restrict__ out,
                      const unsigned char* __restrict__ bp_ws)
{
    const int b    = blockIdx.x;
    const int tid  = threadIdx.x;
    const int lane = tid & 63;
    const int w    = __builtin_amdgcn_readfirstlane(tid >> 6);  // 0..7

    __shared__ int cmap[NCHUNK][KK];
    __shared__ int be_lds[NCHUNK];
    __shared__ unsigned char path_lds[TT];
    __shared__ float red_lds[8];

    const unsigned char* bpb = bp_ws + (size_t)b * TT * KK;

    // ---- chunk-map composition: wave w composes chunks 4w..4w+3 ----
    {
        const int c0 = w * 4;
        const unsigned char* q0 = bpb + (size_t)(c0 + 0) * CHUNK * KK + lane;
        const unsigned char* q1 = bpb + (size_t)(c0 + 1) * CHUNK * KK + lane;
        const unsigned char* q2 = bpb + (size_t)(c0 + 2) * CHUNK * KK + lane;
        const unsigned char* q3 = bpb + (size_t)(c0 + 3) * CHUNK * KK + lane;
        int M0 = lane, M1 = lane, M2 = lane, M3 = lane;
        int a0 = q0[0], a1 = q1[0], a2 = q2[0], a3 = q3[0];
        int b0 = q0[KK], b1 = q1[KK], b2 = q2[KK], b3 = q3[KK];
        for (int t = 0; t < CHUNK; t += 2) {
            int n0 = 0, n1 = 0, n2 = 0, n3 = 0, m0 = 0, m1 = 0, m2 = 0, m3 = 0;
            if (t + 2 < CHUNK) {
                n0 = q0[(t + 2) * KK]; n1 = q1[(t + 2) * KK];
                n2 = q2[(t + 2) * KK]; n3 = q3[(t + 2) * KK];
                m0 = q0[(t + 3) * KK]; m1 = q1[(t + 3) * KK];
                m2 = q2[(t + 3) * KK]; m3 = q3[(t + 3) * KK];
            }
            M0 = __shfl(M0, a0); M1 = __shfl(M1, a1);
            M2 = __shfl(M2, a2); M3 = __shfl(M3, a3);
            M0 = __shfl(M0, b0); M1 = __shfl(M1, b1);
            M2 = __shfl(M2, b2); M3 = __shfl(M3, b3);
            a0 = n0; a1 = n1; a2 = n2; a3 = n3;
            b0 = m0; b1 = m1; b2 = m2; b3 = m3;
        }
        cmap[c0 + 0][lane] = M0; cmap[c0 + 1][lane] = M1;
        cmap[c0 + 2][lane] = M2; cmap[c0 + 3][lane] = M3;
    }
    __syncthreads();

    // ---- chunk-boundary tags (serial, 32 LDS hops) ----
    if (tid == 0) {
        int x = (int)out[b];          // bestlast from k1
        be_lds[NCHUNK - 1] = x;
        for (int c = NCHUNK - 1; c >= 1; --c) {
            x = cmap[c][x];
            be_lds[c - 1] = x;
        }
    }
    __syncthreads();

    // ---- parallel interior backtrace (32 chunks), also fill path_lds ----
    if (tid < NCHUNK) {
        const int c = tid;
        int x = be_lds[c];
        float* po = out + BB + (size_t)b * TT;
        for (int t = (c + 1) * CHUNK - 1; t >= c * CHUNK; --t) {
            po[t] = (float)x;
            path_lds[t] = (unsigned char)x;
            x = (int)bpb[(size_t)t * KK + x];
        }
    }
    __syncthreads();

    // ---- exact score recompute along the decoded path ----
    const float* fbb = feats + (size_t)b * TT * KK;
    const int start_tag = *start_tag_p;
    const int stop_tag  = *stop_tag_p;
    float acc = 0.0f;
    for (int t = tid; t < TT; t += 512) {
        const int xt = path_lds[t];
        const int xp = (t > 0) ? (int)path_lds[t - 1] : start_tag;
        acc += fbb[(size_t)t * KK + xt] + trans[xt * KK + xp];
    }
    if (tid == 0) acc += trans[stop_tag * KK + (int)path_lds[TT - 1]];
#pragma unroll
    for (int off = 1; off < 64; off <<= 1) acc += __shfl_xor(acc, off);
    if (lane == 0) red_lds[w] = acc;
    __syncthreads();
    if (tid == 0) {
        float sc = 0.0f;
        for (int i = 0; i < 8; ++i) sc += red_lds[i];
        out[b] = sc;
    }
}

extern "C" void kernel_launch(void* const* d_in, const int* in_sizes, int n_in,
                              void* d_out, int out_size, void* d_ws, size_t ws_size,
                              hipStream_t stream) {
    const float* feats = (const float*)d_in[0];
    const float* trans = (const float*)d_in[1];
    const int* start_tag = (const int*)d_in[2];
    const int* stop_tag  = (const int*)d_in[3];
    float* out = (float*)d_out;
    unsigned char* bp = (unsigned char*)d_ws;   // B*T*K = 33.5 MB backpointers

    viterbi_fwd_seg<<<BB * NSEG, 512, 0, stream>>>(feats, trans, start_tag, stop_tag, out, bp);
    viterbi_bt_score<<<BB, 512, 0, stream>>>(feats, trans, start_tag, stop_tag, out, bp);
}

// Round 11
// 267.830 us; speedup vs baseline: 2.9231x; 1.3505x over previous
//
#include <hip/hip_runtime.h>
#include <stdint.h>

#define BB 256
#define TT 2048
#define KK 64
#define CHUNK 64
#define NCHUNK (TT / CHUNK)   // 32
#define WLEN 32
#define WARM 96               // 3 windows
#define NSEG 8
#define SEGLEN (TT / NSEG)    // 256
#define NEG_INF_F (-10000.0f)

// DPP quad_perm ctrl codes
#define DPP_XOR1 0xB1   // quad_perm [1,0,3,2]
#define DPP_XOR2 0x4E   // quad_perm [2,3,0,1]

template <int CTRL>
__device__ __forceinline__ unsigned dpp_max_u(unsigned x) {
    int d = __builtin_amdgcn_update_dpp(0, (int)x, CTRL, 0xF, 0xF, true);
    return max(x, (unsigned)d);
}
__device__ __forceinline__ unsigned umax3(unsigned a, unsigned b, unsigned c) {
    return max(max(a, b), c);   // v_max3_u32
}

// LDS-only barrier: never drains vmcnt (bp stores / window loads stay in flight)
__device__ __forceinline__ void lds_barrier() {
    asm volatile("s_waitcnt lgkmcnt(0)\n\ts_barrier" ::: "memory");
}

__device__ __forceinline__ void gload_lds16(const void* g, void* l) {
    __builtin_amdgcn_global_load_lds(
        (const __attribute__((address_space(1))) void*)g,
        (__attribute__((address_space(3))) void*)l, 16, 0, 0);
}

// ============================ kernel 1: forward ============================
// grid 2048: block = (batch b = idx>>3, segment s = idx&7).
// Positive-domain fv (init start=2048, others=512; warm segs all 2048).
// trans clamped at -256 (soft -inf: fv spread << 256 so it never wins).
// Packed-key trick: positive f32 scores compare as u32; low 4 bits carry
// (15 - local_idx) so one u32 max-reduce yields max AND first-argmax.
__global__ __launch_bounds__(256, 8)
void viterbi_fwd_seg(const float* __restrict__ feats,
                     const float* __restrict__ trans,
                     const int* __restrict__ start_tag_p,
                     const int* __restrict__ stop_tag_p,
                     float* __restrict__ out,
                     unsigned char* __restrict__ bp_ws)
{
    const int bid  = blockIdx.x;
    const int b    = bid >> 3;
    const int s    = bid & 7;
    const int t0   = s * SEGLEN - (s ? WARM : 0);
    const int NW   = (SEGLEN + (s ? WARM : 0)) / WLEN;   // 8 or 11
    const int WWARM = s ? (WARM / WLEN) : 0;             // 3 or 0

    const int tid  = threadIdx.x;
    const int lane = tid & 63;
    const int w    = __builtin_amdgcn_readfirstlane(tid >> 6);  // wave 0..3
    const int g    = lane >> 2;        // row within wave (16 rows/wave)
    const int j    = lane & 3;         // p-slice within row (4 x 16)
    const int n    = w * 16 + g;       // owned output row
    const int pbase = j * 16;
    const bool jz  = (j == 0);

    const int start_tag = *start_tag_p;
    const int stop_tag  = *stop_tag_p;

    __shared__ float fv_lds[2][KK];          // double-buffered state (positive domain)
    __shared__ float feat_lds[2][WLEN][KK];  // 16KB feat window double buffer

    const float* fb0 = feats + (size_t)b * TT * KK + (size_t)t0 * KK;
    unsigned char* bpb = bp_ws + (size_t)b * TT * KK;

    // async window stage: wave w fills its 2KB slice, 2 x 1KB issues (linear)
    auto issue_win = [&](int widx, int bufsel) {
        const char* gsrc = (const char*)(fb0 + (size_t)widx * WLEN * KK)
                         + w * 2048 + lane * 16;
        char* ldst = (char*)&feat_lds[bufsel][0][0] + w * 2048;
        gload_lds16(gsrc, ldst);
        gload_lds16(gsrc + 1024, ldst + 1024);
    };
    issue_win(0, 0);

    // per-lane transition fragment trans[n][pbase..pbase+15], soft-inf clamped
    const float4* trp = (const float4*)&trans[n * KK + pbase];
    float4 tA = trp[0], tB = trp[1], tC = trp[2], tD = trp[3];
    tA.x = fmaxf(tA.x, -256.0f); tA.y = fmaxf(tA.y, -256.0f);
    tA.z = fmaxf(tA.z, -256.0f); tA.w = fmaxf(tA.w, -256.0f);
    tB.x = fmaxf(tB.x, -256.0f); tB.y = fmaxf(tB.y, -256.0f);
    tB.z = fmaxf(tB.z, -256.0f); tB.w = fmaxf(tB.w, -256.0f);
    tC.x = fmaxf(tC.x, -256.0f); tC.y = fmaxf(tC.y, -256.0f);
    tC.z = fmaxf(tC.z, -256.0f); tC.w = fmaxf(tC.w, -256.0f);
    tD.x = fmaxf(tD.x, -256.0f); tD.y = fmaxf(tD.y, -256.0f);
    tD.z = fmaxf(tD.z, -256.0f); tD.w = fmaxf(tD.w, -256.0f);
    const float tstop = trans[stop_tag * KK + lane];

    if (tid < KK)
        fv_lds[0][tid] = s ? 2048.0f
                           : ((tid == start_tag) ? 2048.0f : 512.0f);

    __syncthreads();   // drains vmcnt(0): window 0 resident + fv init visible
    issue_win(1, 1);

#define KEYOF(x, inv) ((unsigned)((__float_as_int(x) & 0xFFFFFFF0) | (inv)))

    auto step = [&](int tau, const float* frow, bool st) {
        const float4* fp = (const float4*)&fv_lds[tau & 1][pbase];
        const float4 fa = fp[0], fc = fp[1], fe = fp[2], fh = fp[3];
        const float featval = frow[n];     // 4-lane broadcast, conflict-free

        // packed keys: value-bits | (15 - local_idx)
        const unsigned k0  = KEYOF(fa.x + tA.x, 15);
        const unsigned k1  = KEYOF(fa.y + tA.y, 14);
        const unsigned k2  = KEYOF(fa.z + tA.z, 13);
        const unsigned k3  = KEYOF(fa.w + tA.w, 12);
        const unsigned k4  = KEYOF(fc.x + tB.x, 11);
        const unsigned k5  = KEYOF(fc.y + tB.y, 10);
        const unsigned k6  = KEYOF(fc.z + tB.z,  9);
        const unsigned k7  = KEYOF(fc.w + tB.w,  8);
        const unsigned k8  = KEYOF(fe.x + tC.x,  7);
        const unsigned k9  = KEYOF(fe.y + tC.y,  6);
        const unsigned k10 = KEYOF(fe.z + tC.z,  5);
        const unsigned k11 = KEYOF(fe.w + tC.w,  4);
        const unsigned k12 = KEYOF(fh.x + tD.x,  3);
        const unsigned k13 = KEYOF(fh.y + tD.y,  2);
        const unsigned k14 = KEYOF(fh.z + tD.z,  1);
        const unsigned k15 = KEYOF(fh.w + tD.w,  0);

        // in-lane u32 max tree (v_max3_u32-friendly)
        const unsigned m0 = umax3(k0, k1, k2);
        const unsigned m1 = umax3(k3, k4, k5);
        const unsigned m2 = umax3(k6, k7, k8);
        const unsigned m3 = umax3(k9, k10, k11);
        const unsigned m4 = umax3(k12, k13, k14);
        const unsigned kl = max(umax3(umax3(m0, m1, m2), m3, m4), k15);

        // quad reduce (4 lanes/row)
        unsigned K = dpp_max_u<DPP_XOR1>(kl);
        K = dpp_max_u<DPP_XOR2>(K);

        // fv update (truncated max value + feat)
        const float val = __int_as_float((int)(K & 0xFFFFFFF0u));
        if (jz) fv_lds[(tau + 1) & 1][n] = val + featval;

        if (st) {
            // winner lane (smallest j matching K), then local idx from key
            const unsigned long long mb = __ballot(kl == K);
            const unsigned nib = (unsigned)(mb >> (lane & 60)) & 0xFu;
            const int jq = __ffs((int)nib) - 1;
            const int iq = 15 - (int)(K & 0xFu);
            const int p = (jq << 4) | iq;
            if (jz) bpb[(size_t)(t0 + tau) * KK + n] = (unsigned char)p;
        }
        lds_barrier();
    };

    for (int W = 0; W < NW; ++W) {
        const float (*fw)[KK] = feat_lds[W & 1];
        const bool st = (W >= WWARM);
        const int base = W * WLEN;
        for (int tt = 0; tt < WLEN; tt += 4) {
            step(base + tt + 0, fw[tt + 0], st);
            step(base + tt + 1, fw[tt + 1], st);
            step(base + tt + 2, fw[tt + 2], st);
            step(base + tt + 3, fw[tt + 3], st);
        }
        // boundary: window W+1 (issued one window ago) must be resident
        asm volatile("s_waitcnt vmcnt(0)" ::: "memory");
        __builtin_amdgcn_s_barrier();
        if (W + 2 < NW) issue_win(W + 2, W & 1);   // overwrite just-read buffer
    }

    // terminal argmax (last segment): uniform offset cancels in argmax;
    // true score recomputed from the decoded path in kernel 2.
    if (s == NSEG - 1 && w == 0) {
        float bv = fv_lds[((SEGLEN + WARM)) & 1][lane] + tstop;  // 352 even -> buf 0
        int bi = lane;
#pragma unroll
        for (int off = 1; off < 64; off <<= 1) {
            const float ov = __shfl_xor(bv, off);
            const int   oi = __shfl_xor(bi, off);
            const bool take = (ov > bv) || (ov == bv && oi < bi);
            bv = take ? ov : bv;
            bi = take ? oi : bi;
        }
        if (lane == 0) out[b] = (float)bi;   // carrier for bestlast -> k2
    }
}

// ====================== kernel 2: backtrace + score ======================
__global__ __launch_bounds__(512)
void viterbi_bt_score(const float* __restrict__ feats,
                      const float* __restrict__ trans,
                      const int* __restrict__ start_tag_p,
                      const int* __restrict__ stop_tag_p,
                      float* __restrict__ out,
                      const unsigned char* __restrict__ bp_ws)
{
    const int b    = blockIdx.x;
    const int tid  = threadIdx.x;
    const int lane = tid & 63;
    const int w    = __builtin_amdgcn_readfirstlane(tid >> 6);  // 0..7

    __shared__ int cmap[NCHUNK][KK];
    __shared__ int be_lds[NCHUNK];
    __shared__ unsigned char path_lds[TT];
    __shared__ float red_lds[8];

    const unsigned char* bpb = bp_ws + (size_t)b * TT * KK;

    // ---- chunk-map composition: wave w composes chunks 4w..4w+3 ----
    {
        const int c0 = w * 4;
        const unsigned char* q0 = bpb + (size_t)(c0 + 0) * CHUNK * KK + lane;
        const unsigned char* q1 = bpb + (size_t)(c0 + 1) * CHUNK * KK + lane;
        const unsigned char* q2 = bpb + (size_t)(c0 + 2) * CHUNK * KK + lane;
        const unsigned char* q3 = bpb + (size_t)(c0 + 3) * CHUNK * KK + lane;
        int M0 = lane, M1 = lane, M2 = lane, M3 = lane;
        int a0 = q0[0], a1 = q1[0], a2 = q2[0], a3 = q3[0];
        int b0 = q0[KK], b1 = q1[KK], b2 = q2[KK], b3 = q3[KK];
        for (int t = 0; t < CHUNK; t += 2) {
            int n0 = 0, n1 = 0, n2 = 0, n3 = 0, m0 = 0, m1 = 0, m2 = 0, m3 = 0;
            if (t + 2 < CHUNK) {
                n0 = q0[(t + 2) * KK]; n1 = q1[(t + 2) * KK];
                n2 = q2[(t + 2) * KK]; n3 = q3[(t + 2) * KK];
                m0 = q0[(t + 3) * KK]; m1 = q1[(t + 3) * KK];
                m2 = q2[(t + 3) * KK]; m3 = q3[(t + 3) * KK];
            }
            M0 = __shfl(M0, a0); M1 = __shfl(M1, a1);
            M2 = __shfl(M2, a2); M3 = __shfl(M3, a3);
            M0 = __shfl(M0, b0); M1 = __shfl(M1, b1);
            M2 = __shfl(M2, b2); M3 = __shfl(M3, b3);
            a0 = n0; a1 = n1; a2 = n2; a3 = n3;
            b0 = m0; b1 = m1; b2 = m2; b3 = m3;
        }
        cmap[c0 + 0][lane] = M0; cmap[c0 + 1][lane] = M1;
        cmap[c0 + 2][lane] = M2; cmap[c0 + 3][lane] = M3;
    }
    __syncthreads();

    // ---- chunk-boundary tags (serial, 32 LDS hops) ----
    if (tid == 0) {
        int x = (int)out[b];          // bestlast from k1
        be_lds[NCHUNK - 1] = x;
        for (int c = NCHUNK - 1; c >= 1; --c) {
            x = cmap[c][x];
            be_lds[c - 1] = x;
        }
    }
    __syncthreads();

    // ---- parallel interior backtrace (32 chunks), also fill path_lds ----
    if (tid < NCHUNK) {
        const int c = tid;
        int x = be_lds[c];
        float* po = out + BB + (size_t)b * TT;
        for (int t = (c + 1) * CHUNK - 1; t >= c * CHUNK; --t) {
            po[t] = (float)x;
            path_lds[t] = (unsigned char)x;
            x = (int)bpb[(size_t)t * KK + x];
        }
    }
    __syncthreads();

    // ---- exact score recompute along the decoded path ----
    const float* fbb = feats + (size_t)b * TT * KK;
    const int start_tag = *start_tag_p;
    const int stop_tag  = *stop_tag_p;
    float acc = 0.0f;
    for (int t = tid; t < TT; t += 512) {
        const int xt = path_lds[t];
        const int xp = (t > 0) ? (int)path_lds[t - 1] : start_tag;
        acc += fbb[(size_t)t * KK + xt] + trans[xt * KK + xp];
    }
    if (tid == 0) acc += trans[stop_tag * KK + (int)path_lds[TT - 1]];
#pragma unroll
    for (int off = 1; off < 64; off <<= 1) acc += __shfl_xor(acc, off);
    if (lane == 0) red_lds[w] = acc;
    __syncthreads();
    if (tid == 0) {
        float sc = 0.0f;
        for (int i = 0; i < 8; ++i) sc += red_lds[i];
        out[b] = sc;
    }
}

extern "C" void kernel_launch(void* const* d_in, const int* in_sizes, int n_in,
                              void* d_out, int out_size, void* d_ws, size_t ws_size,
                              hipStream_t stream) {
    const float* feats = (const float*)d_in[0];
    const float* trans = (const float*)d_in[1];
    const int* start_tag = (const int*)d_in[2];
    const int* stop_tag  = (const int*)d_in[3];
    float* out = (float*)d_out;
    unsigned char* bp = (unsigned char*)d_ws;   // B*T*K = 33.5 MB backpointers

    viterbi_fwd_seg<<<BB * NSEG, 256, 0, stream>>>(feats, trans, start_tag, stop_tag, out, bp);
    viterbi_bt_score<<<BB, 512, 0, stream>>>(feats, trans, start_tag, stop_tag, out, bp);
}

// Round 12
// 234.245 us; speedup vs baseline: 3.3422x; 1.1434x over previous
//
#include <hip/hip_runtime.h>
#include <stdint.h>

#define BB 256
#define TT 2048
#define KK 64
#define CHUNK 64
#define NCHUNK (TT / CHUNK)   // 32
#define WLEN 16
#define WARM 64               // 4 windows
#define NSEG 8
#define SEGLEN (TT / NSEG)    // 256
#define NEG_INF_F (-10000.0f)

#define DPP_XOR1 0xB1   // quad_perm [1,0,3,2]

template <int CTRL>
__device__ __forceinline__ unsigned dpp_max_u(unsigned x) {
    int d = __builtin_amdgcn_update_dpp(0, (int)x, CTRL, 0xF, 0xF, true);
    return max(x, (unsigned)d);
}
__device__ __forceinline__ unsigned umax3(unsigned a, unsigned b, unsigned c) {
    return max(max(a, b), c);   // v_max3_u32
}

// LDS-only barrier: never drains vmcnt (bp stores / window loads stay in flight)
__device__ __forceinline__ void lds_barrier() {
    asm volatile("s_waitcnt lgkmcnt(0)\n\ts_barrier" ::: "memory");
}

__device__ __forceinline__ void gload_lds16(const void* g, void* l) {
    __builtin_amdgcn_global_load_lds(
        (const __attribute__((address_space(1))) void*)g,
        (__attribute__((address_space(3))) void*)l, 16, 0, 0);
}

// ============================ kernel 1: forward ============================
// grid 2048 x 128 threads: block = (batch b = idx>>3, segment s = idx&7).
// 2 waves/block; lane layout: row n = w*32 + (lane>>1), p-slice j = lane&1
// owning p in [j*32, j*32+32). Positive-domain fv; trans clamped at -256.
// Packed key: value-bits & ~31 | (31 - local_idx) -> one u32 max = max+argmax.
__global__ __launch_bounds__(128, 8)
void viterbi_fwd_seg(const float* __restrict__ feats,
                     const float* __restrict__ trans,
                     const int* __restrict__ start_tag_p,
                     const int* __restrict__ stop_tag_p,
                     float* __restrict__ out,
                     unsigned char* __restrict__ bp_ws)
{
    const int bid  = blockIdx.x;
    const int b    = bid >> 3;
    const int s    = bid & 7;
    const int t0   = s * SEGLEN - (s ? WARM : 0);
    const int NW   = (SEGLEN + (s ? WARM : 0)) / WLEN;   // 16 or 20
    const int WWARM = s ? (WARM / WLEN) : 0;             // 4 or 0

    const int tid  = threadIdx.x;
    const int lane = tid & 63;
    const int w    = __builtin_amdgcn_readfirstlane(tid >> 6);  // wave 0..1
    const int g    = lane >> 1;        // row within wave (32 rows/wave)
    const int j    = lane & 1;         // p-slice within row (2 x 32)
    const int n    = w * 32 + g;       // owned output row
    const int pbase = j * 32;
    const bool jz  = (j == 0);

    const int start_tag = *start_tag_p;
    const int stop_tag  = *stop_tag_p;

    __shared__ float fv_lds[2][KK];          // double-buffered state (positive domain)
    __shared__ float feat_lds[2][WLEN][KK];  // 8KB feat window double buffer

    const float* fb0 = feats + (size_t)b * TT * KK + (size_t)t0 * KK;
    unsigned char* bpb = bp_ws + (size_t)b * TT * KK;

    // async window stage: wave w fills its 2KB slice, 2 x 1KB issues (linear)
    auto issue_win = [&](int widx, int bufsel) {
        const char* gsrc = (const char*)(fb0 + (size_t)widx * WLEN * KK)
                         + w * 2048 + lane * 16;
        char* ldst = (char*)&feat_lds[bufsel][0][0] + w * 2048;
        gload_lds16(gsrc, ldst);
        gload_lds16(gsrc + 1024, ldst + 1024);
    };
    issue_win(0, 0);

    // per-lane transition fragment trans[n][pbase..pbase+31], soft-inf clamped
    const float4* trp = (const float4*)&trans[n * KK + pbase];
    float4 tr[8];
#pragma unroll
    for (int q = 0; q < 8; ++q) {
        tr[q] = trp[q];
        tr[q].x = fmaxf(tr[q].x, -256.0f);
        tr[q].y = fmaxf(tr[q].y, -256.0f);
        tr[q].z = fmaxf(tr[q].z, -256.0f);
        tr[q].w = fmaxf(tr[q].w, -256.0f);
    }
    const float tstop = trans[stop_tag * KK + lane];

    if (tid < KK)
        fv_lds[0][tid] = s ? 2048.0f
                           : ((tid == start_tag) ? 2048.0f : 512.0f);

    __syncthreads();   // drains vmcnt(0): window 0 resident + fv init visible
    issue_win(1, 1);

#define KEY5(x, inv) ((unsigned)((__float_as_int(x) & 0xFFFFFFE0) | (inv)))

    auto step = [&](int tau, const float* frow, bool st) {
        const float4* fp = (const float4*)&fv_lds[tau & 1][pbase];
        const float featval = frow[n];     // 2-lane broadcast, conflict-free

        // half 0: local idx 0..15 (inv 31..16), computed then reduced (caps VGPRs)
        unsigned kl;
        {
            const float4 f0 = fp[0], f1 = fp[1], f2 = fp[2], f3 = fp[3];
            const unsigned k0  = KEY5(f0.x + tr[0].x, 31);
            const unsigned k1  = KEY5(f0.y + tr[0].y, 30);
            const unsigned k2  = KEY5(f0.z + tr[0].z, 29);
            const unsigned k3  = KEY5(f0.w + tr[0].w, 28);
            const unsigned k4  = KEY5(f1.x + tr[1].x, 27);
            const unsigned k5  = KEY5(f1.y + tr[1].y, 26);
            const unsigned k6  = KEY5(f1.z + tr[1].z, 25);
            const unsigned k7  = KEY5(f1.w + tr[1].w, 24);
            const unsigned k8  = KEY5(f2.x + tr[2].x, 23);
            const unsigned k9  = KEY5(f2.y + tr[2].y, 22);
            const unsigned k10 = KEY5(f2.z + tr[2].z, 21);
            const unsigned k11 = KEY5(f2.w + tr[2].w, 20);
            const unsigned k12 = KEY5(f3.x + tr[3].x, 19);
            const unsigned k13 = KEY5(f3.y + tr[3].y, 18);
            const unsigned k14 = KEY5(f3.z + tr[3].z, 17);
            const unsigned k15 = KEY5(f3.w + tr[3].w, 16);
            const unsigned m0 = umax3(k0, k1, k2);
            const unsigned m1 = umax3(k3, k4, k5);
            const unsigned m2 = umax3(k6, k7, k8);
            const unsigned m3 = umax3(k9, k10, k11);
            const unsigned m4 = umax3(k12, k13, k14);
            kl = max(umax3(umax3(m0, m1, m2), m3, m4), k15);
        }
        // half 1: local idx 16..31 (inv 15..0)
        {
            const float4 f4 = fp[4], f5 = fp[5], f6 = fp[6], f7 = fp[7];
            const unsigned k0  = KEY5(f4.x + tr[4].x, 15);
            const unsigned k1  = KEY5(f4.y + tr[4].y, 14);
            const unsigned k2  = KEY5(f4.z + tr[4].z, 13);
            const unsigned k3  = KEY5(f4.w + tr[4].w, 12);
            const unsigned k4  = KEY5(f5.x + tr[5].x, 11);
            const unsigned k5  = KEY5(f5.y + tr[5].y, 10);
            const unsigned k6  = KEY5(f5.z + tr[5].z,  9);
            const unsigned k7  = KEY5(f5.w + tr[5].w,  8);
            const unsigned k8  = KEY5(f6.x + tr[6].x,  7);
            const unsigned k9  = KEY5(f6.y + tr[6].y,  6);
            const unsigned k10 = KEY5(f6.z + tr[6].z,  5);
            const unsigned k11 = KEY5(f6.w + tr[6].w,  4);
            const unsigned k12 = KEY5(f7.x + tr[7].x,  3);
            const unsigned k13 = KEY5(f7.y + tr[7].y,  2);
            const unsigned k14 = KEY5(f7.z + tr[7].z,  1);
            const unsigned k15 = KEY5(f7.w + tr[7].w,  0);
            const unsigned m0 = umax3(k0, k1, k2);
            const unsigned m1 = umax3(k3, k4, k5);
            const unsigned m2 = umax3(k6, k7, k8);
            const unsigned m3 = umax3(k9, k10, k11);
            const unsigned m4 = umax3(k12, k13, k14);
            kl = max(kl, max(umax3(umax3(m0, m1, m2), m3, m4), k15));
        }

        // row reduce (2 lanes)
        const unsigned K = dpp_max_u<DPP_XOR1>(kl);

        // fv update (truncated max value + feat)
        if (jz) fv_lds[(tau + 1) & 1][n] =
            __int_as_float((int)(K & 0xFFFFFFE0u)) + featval;

        if (st) {
            // winner lane (j=0 preferred), local idx from key low bits
            const unsigned long long mb = __ballot(kl == K);
            const unsigned pr = (unsigned)(mb >> (lane & 62)) & 3u;
            const int jq = __ffs((int)pr) - 1;
            const int iq = 31 - (int)(K & 31u);
            const int p = (jq << 5) | iq;
            if (jz) bpb[(size_t)(t0 + tau) * KK + n] = (unsigned char)p;
        }
        lds_barrier();
    };

    for (int W = 0; W < NW; ++W) {
        const float (*fw)[KK] = feat_lds[W & 1];
        const bool st = (W >= WWARM);
        const int base = W * WLEN;
        for (int tt = 0; tt < WLEN; tt += 4) {
            step(base + tt + 0, fw[tt + 0], st);
            step(base + tt + 1, fw[tt + 1], st);
            step(base + tt + 2, fw[tt + 2], st);
            step(base + tt + 3, fw[tt + 3], st);
        }
        // boundary: window W+1 (issued one window ago) must be resident
        asm volatile("s_waitcnt vmcnt(0)" ::: "memory");
        __builtin_amdgcn_s_barrier();
        if (W + 2 < NW) issue_win(W + 2, W & 1);   // overwrite just-read buffer
    }

    // terminal argmax (last segment): uniform offset cancels in argmax;
    // true score recomputed from the decoded path in kernel 2.
    if (s == NSEG - 1 && w == 0) {
        float bv = fv_lds[(SEGLEN + WARM) & 1][lane] + tstop;  // 320 even -> buf 0
        int bi = lane;
#pragma unroll
        for (int off = 1; off < 64; off <<= 1) {
            const float ov = __shfl_xor(bv, off);
            const int   oi = __shfl_xor(bi, off);
            const bool take = (ov > bv) || (ov == bv && oi < bi);
            bv = take ? ov : bv;
            bi = take ? oi : bi;
        }
        if (lane == 0) out[b] = (float)bi;   // carrier for bestlast -> k2
    }
}

// ====================== kernel 2: backtrace + score ======================
__global__ __launch_bounds__(512)
void viterbi_bt_score(const float* __restrict__ feats,
                      const float* __restrict__ trans,
                      const int* __restrict__ start_tag_p,
                      const int* __restrict__ stop_tag_p,
                      float* __restrict__ out,
                      const unsigned char* __restrict__ bp_ws)
{
    const int b    = blockIdx.x;
    const int tid  = threadIdx.x;
    const int lane = tid & 63;
    const int w    = __builtin_amdgcn_readfirstlane(tid >> 6);  // 0..7

    __shared__ int cmap[NCHUNK][KK];
    __shared__ int be_lds[NCHUNK];
    __shared__ unsigned char path_lds[TT];
    __shared__ float red_lds[8];

    const unsigned char* bpb = bp_ws + (size_t)b * TT * KK;

    // ---- chunk-map composition: wave w composes chunks 4w..4w+3 ----
    {
        const int c0 = w * 4;
        const unsigned char* q0 = bpb + (size_t)(c0 + 0) * CHUNK * KK + lane;
        const unsigned char* q1 = bpb + (size_t)(c0 + 1) * CHUNK * KK + lane;
        const unsigned char* q2 = bpb + (size_t)(c0 + 2) * CHUNK * KK + lane;
        const unsigned char* q3 = bpb + (size_t)(c0 + 3) * CHUNK * KK + lane;
        int M0 = lane, M1 = lane, M2 = lane, M3 = lane;
        int a0 = q0[0], a1 = q1[0], a2 = q2[0], a3 = q3[0];
        int b0 = q0[KK], b1 = q1[KK], b2 = q2[KK], b3 = q3[KK];
        for (int t = 0; t < CHUNK; t += 2) {
            int n0 = 0, n1 = 0, n2 = 0, n3 = 0, m0 = 0, m1 = 0, m2 = 0, m3 = 0;
            if (t + 2 < CHUNK) {
                n0 = q0[(t + 2) * KK]; n1 = q1[(t + 2) * KK];
                n2 = q2[(t + 2) * KK]; n3 = q3[(t + 2) * KK];
                m0 = q0[(t + 3) * KK]; m1 = q1[(t + 3) * KK];
                m2 = q2[(t + 3) * KK]; m3 = q3[(t + 3) * KK];
            }
            M0 = __shfl(M0, a0); M1 = __shfl(M1, a1);
            M2 = __shfl(M2, a2); M3 = __shfl(M3, a3);
            M0 = __shfl(M0, b0); M1 = __shfl(M1, b1);
            M2 = __shfl(M2, b2); M3 = __shfl(M3, b3);
            a0 = n0; a1 = n1; a2 = n2; a3 = n3;
            b0 = m0; b1 = m1; b2 = m2; b3 = m3;
        }
        cmap[c0 + 0][lane] = M0; cmap[c0 + 1][lane] = M1;
        cmap[c0 + 2][lane] = M2; cmap[c0 + 3][lane] = M3;
    }
    __syncthreads();

    // ---- chunk-boundary tags (serial, 32 LDS hops) ----
    if (tid == 0) {
        int x = (int)out[b];          // bestlast from k1
        be_lds[NCHUNK - 1] = x;
        for (int c = NCHUNK - 1; c >= 1; --c) {
            x = cmap[c][x];
            be_lds[c - 1] = x;
        }
    }
    __syncthreads();

    // ---- parallel interior backtrace (32 chunks), also fill path_lds ----
    if (tid < NCHUNK) {
        const int c = tid;
        int x = be_lds[c];
        float* po = out + BB + (size_t)b * TT;
        for (int t = (c + 1) * CHUNK - 1; t >= c * CHUNK; --t) {
            po[t] = (float)x;
            path_lds[t] = (unsigned char)x;
            x = (int)bpb[(size_t)t * KK + x];
        }
    }
    __syncthreads();

    // ---- exact score recompute along the decoded path ----
    const float* fbb = feats + (size_t)b * TT * KK;
    const int start_tag = *start_tag_p;
    const int stop_tag  = *stop_tag_p;
    float acc = 0.0f;
    for (int t = tid; t < TT; t += 512) {
        const int xt = path_lds[t];
        const int xp = (t > 0) ? (int)path_lds[t - 1] : start_tag;
        acc += fbb[(size_t)t * KK + xt] + trans[xt * KK + xp];
    }
    if (tid == 0) acc += trans[stop_tag * KK + (int)path_lds[TT - 1]];
#pragma unroll
    for (int off = 1; off < 64; off <<= 1) acc += __shfl_xor(acc, off);
    if (lane == 0) red_lds[w] = acc;
    __syncthreads();
    if (tid == 0) {
        float sc = 0.0f;
        for (int i = 0; i < 8; ++i) sc += red_lds[i];
        out[b] = sc;
    }
}

extern "C" void kernel_launch(void* const* d_in, const int* in_sizes, int n_in,
                              void* d_out, int out_size, void* d_ws, size_t ws_size,
                              hipStream_t stream) {
    const float* feats = (const float*)d_in[0];
    const float* trans = (const float*)d_in[1];
    const int* start_tag = (const int*)d_in[2];
    const int* stop_tag  = (const int*)d_in[3];
    float* out = (float*)d_out;
    unsigned char* bp = (unsigned char*)d_ws;   // B*T*K = 33.5 MB backpointers

    viterbi_fwd_seg<<<BB * NSEG, 128, 0, stream>>>(feats, trans, start_tag, stop_tag, out, bp);
    viterbi_bt_score<<<BB, 512, 0, stream>>>(feats, trans, start_tag, stop_tag, out, bp);
}

// Round 13
// 208.685 us; speedup vs baseline: 3.7516x; 1.1225x over previous
//
#include <hip/hip_runtime.h>
#include <stdint.h>

#define BB 256
#define TT 2048
#define KK 64
#define CHUNK 64
#define NCHUNK (TT / CHUNK)   // 32
#define WLEN 16
#define WARM 32               // 2 windows
#define NSEG 16
#define SEGLEN (TT / NSEG)    // 128
#define NEG_INF_F (-10000.0f)

#define DPP_XOR1 0xB1   // quad_perm [1,0,3,2]

template <int CTRL>
__device__ __forceinline__ unsigned dpp_max_u(unsigned x) {
    int d = __builtin_amdgcn_update_dpp(0, (int)x, CTRL, 0xF, 0xF, true);
    return max(x, (unsigned)d);
}
__device__ __forceinline__ unsigned umax3(unsigned a, unsigned b, unsigned c) {
    return max(max(a, b), c);   // v_max3_u32
}

// LDS-only barrier: never drains vmcnt (bp stores / window loads stay in flight)
__device__ __forceinline__ void lds_barrier() {
    asm volatile("s_waitcnt lgkmcnt(0)\n\ts_barrier" ::: "memory");
}

__device__ __forceinline__ void gload_lds16(const void* g, void* l) {
    __builtin_amdgcn_global_load_lds(
        (const __attribute__((address_space(1))) void*)g,
        (__attribute__((address_space(3))) void*)l, 16, 0, 0);
}

// ============================ kernel 1: forward ============================
// grid 4096 x 128 threads: block = (batch b = idx>>4, segment s = idx&15).
// 2 waves/block; lane layout: row n = w*32 + (lane>>1), p-slice j = lane&1
// owning p in [j*32, j*32+32). Positive-domain fv; trans clamped at -256.
// Packed key: value-bits & ~31 | (31 - local_idx) -> one u32 max = max+argmax.
__global__ __launch_bounds__(128, 8)
void viterbi_fwd_seg(const float* __restrict__ feats,
                     const float* __restrict__ trans,
                     const int* __restrict__ start_tag_p,
                     const int* __restrict__ stop_tag_p,
                     float* __restrict__ out,
                     unsigned char* __restrict__ bp_ws)
{
    const int bid  = blockIdx.x;
    const int b    = bid >> 4;
    const int s    = bid & 15;
    const int t0   = s * SEGLEN - (s ? WARM : 0);
    const int NW   = (SEGLEN + (s ? WARM : 0)) / WLEN;   // 8 or 10
    const int WWARM = s ? (WARM / WLEN) : 0;             // 2 or 0

    const int tid  = threadIdx.x;
    const int lane = tid & 63;
    const int w    = __builtin_amdgcn_readfirstlane(tid >> 6);  // wave 0..1
    const int g    = lane >> 1;        // row within wave (32 rows/wave)
    const int j    = lane & 1;         // p-slice within row (2 x 32)
    const int n    = w * 32 + g;       // owned output row
    const int pbase = j * 32;
    const bool jz  = (j == 0);

    const int start_tag = *start_tag_p;
    const int stop_tag  = *stop_tag_p;

    __shared__ float fv_lds[2][KK];          // double-buffered state (positive domain)
    __shared__ float feat_lds[2][WLEN][KK];  // 8KB feat window double buffer

    const float* fb0 = feats + (size_t)b * TT * KK + (size_t)t0 * KK;
    unsigned char* bpb = bp_ws + (size_t)b * TT * KK;

    // async window stage: wave w fills its 2KB slice, 2 x 1KB issues (linear)
    auto issue_win = [&](int widx, int bufsel) {
        const char* gsrc = (const char*)(fb0 + (size_t)widx * WLEN * KK)
                         + w * 2048 + lane * 16;
        char* ldst = (char*)&feat_lds[bufsel][0][0] + w * 2048;
        gload_lds16(gsrc, ldst);
        gload_lds16(gsrc + 1024, ldst + 1024);
    };
    issue_win(0, 0);

    // per-lane transition fragment trans[n][pbase..pbase+31], soft-inf clamped
    const float4* trp = (const float4*)&trans[n * KK + pbase];
    float4 tr[8];
#pragma unroll
    for (int q = 0; q < 8; ++q) {
        tr[q] = trp[q];
        tr[q].x = fmaxf(tr[q].x, -256.0f);
        tr[q].y = fmaxf(tr[q].y, -256.0f);
        tr[q].z = fmaxf(tr[q].z, -256.0f);
        tr[q].w = fmaxf(tr[q].w, -256.0f);
    }
    const float tstop = trans[stop_tag * KK + lane];

    if (tid < KK)
        fv_lds[0][tid] = s ? 2048.0f
                           : ((tid == start_tag) ? 2048.0f : 512.0f);

    __syncthreads();   // drains vmcnt(0): window 0 resident + fv init visible
    issue_win(1, 1);

#define KEY5(x, inv) ((unsigned)((__float_as_int(x) & 0xFFFFFFE0) | (inv)))

    auto step = [&](int tau, const float* frow, bool st) {
        const float4* fp = (const float4*)&fv_lds[tau & 1][pbase];
        const float featval = frow[n];     // 2-lane broadcast, conflict-free

        // half 0: local idx 0..15 (inv 31..16), computed then reduced (caps VGPRs)
        unsigned kl;
        {
            const float4 f0 = fp[0], f1 = fp[1], f2 = fp[2], f3 = fp[3];
            const unsigned k0  = KEY5(f0.x + tr[0].x, 31);
            const unsigned k1  = KEY5(f0.y + tr[0].y, 30);
            const unsigned k2  = KEY5(f0.z + tr[0].z, 29);
            const unsigned k3  = KEY5(f0.w + tr[0].w, 28);
            const unsigned k4  = KEY5(f1.x + tr[1].x, 27);
            const unsigned k5  = KEY5(f1.y + tr[1].y, 26);
            const unsigned k6  = KEY5(f1.z + tr[1].z, 25);
            const unsigned k7  = KEY5(f1.w + tr[1].w, 24);
            const unsigned k8  = KEY5(f2.x + tr[2].x, 23);
            const unsigned k9  = KEY5(f2.y + tr[2].y, 22);
            const unsigned k10 = KEY5(f2.z + tr[2].z, 21);
            const unsigned k11 = KEY5(f2.w + tr[2].w, 20);
            const unsigned k12 = KEY5(f3.x + tr[3].x, 19);
            const unsigned k13 = KEY5(f3.y + tr[3].y, 18);
            const unsigned k14 = KEY5(f3.z + tr[3].z, 17);
            const unsigned k15 = KEY5(f3.w + tr[3].w, 16);
            const unsigned m0 = umax3(k0, k1, k2);
            const unsigned m1 = umax3(k3, k4, k5);
            const unsigned m2 = umax3(k6, k7, k8);
            const unsigned m3 = umax3(k9, k10, k11);
            const unsigned m4 = umax3(k12, k13, k14);
            kl = max(umax3(umax3(m0, m1, m2), m3, m4), k15);
        }
        // half 1: local idx 16..31 (inv 15..0)
        {
            const float4 f4 = fp[4], f5 = fp[5], f6 = fp[6], f7 = fp[7];
            const unsigned k0  = KEY5(f4.x + tr[4].x, 15);
            const unsigned k1  = KEY5(f4.y + tr[4].y, 14);
            const unsigned k2  = KEY5(f4.z + tr[4].z, 13);
            const unsigned k3  = KEY5(f4.w + tr[4].w, 12);
            const unsigned k4  = KEY5(f5.x + tr[5].x, 11);
            const unsigned k5  = KEY5(f5.y + tr[5].y, 10);
            const unsigned k6  = KEY5(f5.z + tr[5].z,  9);
            const unsigned k7  = KEY5(f5.w + tr[5].w,  8);
            const unsigned k8  = KEY5(f6.x + tr[6].x,  7);
            const unsigned k9  = KEY5(f6.y + tr[6].y,  6);
            const unsigned k10 = KEY5(f6.z + tr[6].z,  5);
            const unsigned k11 = KEY5(f6.w + tr[6].w,  4);
            const unsigned k12 = KEY5(f7.x + tr[7].x,  3);
            const unsigned k13 = KEY5(f7.y + tr[7].y,  2);
            const unsigned k14 = KEY5(f7.z + tr[7].z,  1);
            const unsigned k15 = KEY5(f7.w + tr[7].w,  0);
            const unsigned m0 = umax3(k0, k1, k2);
            const unsigned m1 = umax3(k3, k4, k5);
            const unsigned m2 = umax3(k6, k7, k8);
            const unsigned m3 = umax3(k9, k10, k11);
            const unsigned m4 = umax3(k12, k13, k14);
            kl = max(kl, max(umax3(umax3(m0, m1, m2), m3, m4), k15));
        }

        // row reduce (2 lanes)
        const unsigned K = dpp_max_u<DPP_XOR1>(kl);

        // fv update (truncated max value + feat)
        if (jz) fv_lds[(tau + 1) & 1][n] =
            __int_as_float((int)(K & 0xFFFFFFE0u)) + featval;

        if (st) {
            // winner lane (j=0 preferred), local idx from key low bits
            const unsigned long long mb = __ballot(kl == K);
            const unsigned pr = (unsigned)(mb >> (lane & 62)) & 3u;
            const int jq = __ffs((int)pr) - 1;
            const int iq = 31 - (int)(K & 31u);
            const int p = (jq << 5) | iq;
            if (jz) bpb[(size_t)(t0 + tau) * KK + n] = (unsigned char)p;
        }
        lds_barrier();
    };

    for (int W = 0; W < NW; ++W) {
        const float (*fw)[KK] = feat_lds[W & 1];
        const bool st = (W >= WWARM);
        const int base = W * WLEN;
        for (int tt = 0; tt < WLEN; tt += 4) {
            step(base + tt + 0, fw[tt + 0], st);
            step(base + tt + 1, fw[tt + 1], st);
            step(base + tt + 2, fw[tt + 2], st);
            step(base + tt + 3, fw[tt + 3], st);
        }
        // boundary: window W+1 (issued one window ago) must be resident
        asm volatile("s_waitcnt vmcnt(0)" ::: "memory");
        __builtin_amdgcn_s_barrier();
        if (W + 2 < NW) issue_win(W + 2, W & 1);   // overwrite just-read buffer
    }

    // terminal argmax (last segment): uniform offset cancels in argmax;
    // true score recomputed from the decoded path in kernel 2.
    if (s == NSEG - 1 && w == 0) {
        float bv = fv_lds[(SEGLEN + WARM) & 1][lane] + tstop;  // 160 even -> buf 0
        int bi = lane;
#pragma unroll
        for (int off = 1; off < 64; off <<= 1) {
            const float ov = __shfl_xor(bv, off);
            const int   oi = __shfl_xor(bi, off);
            const bool take = (ov > bv) || (ov == bv && oi < bi);
            bv = take ? ov : bv;
            bi = take ? oi : bi;
        }
        if (lane == 0) out[b] = (float)bi;   // carrier for bestlast -> k2
    }
}

// ====================== kernel 2: backtrace + score ======================
__global__ __launch_bounds__(512)
void viterbi_bt_score(const float* __restrict__ feats,
                      const float* __restrict__ trans,
                      const int* __restrict__ start_tag_p,
                      const int* __restrict__ stop_tag_p,
                      float* __restrict__ out,
                      const unsigned char* __restrict__ bp_ws)
{
    const int b    = blockIdx.x;
    const int tid  = threadIdx.x;
    const int lane = tid & 63;
    const int w    = __builtin_amdgcn_readfirstlane(tid >> 6);  // 0..7

    __shared__ int cmap[NCHUNK][KK];
    __shared__ int be_lds[NCHUNK];
    __shared__ unsigned char path_lds[TT];
    __shared__ float red_lds[8];

    const unsigned char* bpb = bp_ws + (size_t)b * TT * KK;

    // ---- chunk-map composition: wave w composes chunks 4w..4w+3 ----
    {
        const int c0 = w * 4;
        const unsigned char* q0 = bpb + (size_t)(c0 + 0) * CHUNK * KK + lane;
        const unsigned char* q1 = bpb + (size_t)(c0 + 1) * CHUNK * KK + lane;
        const unsigned char* q2 = bpb + (size_t)(c0 + 2) * CHUNK * KK + lane;
        const unsigned char* q3 = bpb + (size_t)(c0 + 3) * CHUNK * KK + lane;
        int M0 = lane, M1 = lane, M2 = lane, M3 = lane;
        int a0 = q0[0], a1 = q1[0], a2 = q2[0], a3 = q3[0];
        int b0 = q0[KK], b1 = q1[KK], b2 = q2[KK], b3 = q3[KK];
        for (int t = 0; t < CHUNK; t += 2) {
            int n0 = 0, n1 = 0, n2 = 0, n3 = 0, m0 = 0, m1 = 0, m2 = 0, m3 = 0;
            if (t + 2 < CHUNK) {
                n0 = q0[(t + 2) * KK]; n1 = q1[(t + 2) * KK];
                n2 = q2[(t + 2) * KK]; n3 = q3[(t + 2) * KK];
                m0 = q0[(t + 3) * KK]; m1 = q1[(t + 3) * KK];
                m2 = q2[(t + 3) * KK]; m3 = q3[(t + 3) * KK];
            }
            M0 = __shfl(M0, a0); M1 = __shfl(M1, a1);
            M2 = __shfl(M2, a2); M3 = __shfl(M3, a3);
            M0 = __shfl(M0, b0); M1 = __shfl(M1, b1);
            M2 = __shfl(M2, b2); M3 = __shfl(M3, b3);
            a0 = n0; a1 = n1; a2 = n2; a3 = n3;
            b0 = m0; b1 = m1; b2 = m2; b3 = m3;
        }
        cmap[c0 + 0][lane] = M0; cmap[c0 + 1][lane] = M1;
        cmap[c0 + 2][lane] = M2; cmap[c0 + 3][lane] = M3;
    }
    __syncthreads();

    // ---- chunk-boundary tags (serial, 32 LDS hops) ----
    if (tid == 0) {
        int x = (int)out[b];          // bestlast from k1
        be_lds[NCHUNK - 1] = x;
        for (int c = NCHUNK - 1; c >= 1; --c) {
            x = cmap[c][x];
            be_lds[c - 1] = x;
        }
    }
    __syncthreads();

    // ---- parallel interior backtrace (32 chunks), also fill path_lds ----
    if (tid < NCHUNK) {
        const int c = tid;
        int x = be_lds[c];
        float* po = out + BB + (size_t)b * TT;
        for (int t = (c + 1) * CHUNK - 1; t >= c * CHUNK; --t) {
            po[t] = (float)x;
            path_lds[t] = (unsigned char)x;
            x = (int)bpb[(size_t)t * KK + x];
        }
    }
    __syncthreads();

    // ---- exact score recompute along the decoded path ----
    const float* fbb = feats + (size_t)b * TT * KK;
    const int start_tag = *start_tag_p;
    const int stop_tag  = *stop_tag_p;
    float acc = 0.0f;
    for (int t = tid; t < TT; t += 512) {
        const int xt = path_lds[t];
        const int xp = (t > 0) ? (int)path_lds[t - 1] : start_tag;
        acc += fbb[(size_t)t * KK + xt] + trans[xt * KK + xp];
    }
    if (tid == 0) acc += trans[stop_tag * KK + (int)path_lds[TT - 1]];
#pragma unroll
    for (int off = 1; off < 64; off <<= 1) acc += __shfl_xor(acc, off);
    if (lane == 0) red_lds[w] = acc;
    __syncthreads();
    if (tid == 0) {
        float sc = 0.0f;
        for (int i = 0; i < 8; ++i) sc += red_lds[i];
        out[b] = sc;
    }
}

extern "C" void kernel_launch(void* const* d_in, const int* in_sizes, int n_in,
                              void* d_out, int out_size, void* d_ws, size_t ws_size,
                              hipStream_t stream) {
    const float* feats = (const float*)d_in[0];
    const float* trans = (const float*)d_in[1];
    const int* start_tag = (const int*)d_in[2];
    const int* stop_tag  = (const int*)d_in[3];
    float* out = (float*)d_out;
    unsigned char* bp = (unsigned char*)d_ws;   // B*T*K = 33.5 MB backpointers

    viterbi_fwd_seg<<<BB * NSEG, 128, 0, stream>>>(feats, trans, start_tag, stop_tag, out, bp);
    viterbi_bt_score<<<BB, 512, 0, stream>>>(feats, trans, start_tag, stop_tag, out, bp);
}